// Round 1
// baseline (2126.959 us; speedup 1.0000x reference)
//
#include <hip/hip_runtime.h>

// ---------------- constants ----------------
#define BWIN 2048
#define NKV  49      // kv rows per window
#define DIM  384
#define NH   12
#define HD   32
#define QN   196     // q rows per window
#define KQ   192     // q input width (DIM/CS)
#define SCALE 0.17677669529663687f

// strides (elements) chosen: multiple of 8 (16B frag alignment), %32dw gives <=2-way LDS bank aliasing
#define QS_STR  200  // 196x200 bf16
#define KVS_STR 392  // 49x392 bf16
#define KS_STR  40   // 49x40
#define VT_STR  72   // 32x72 (kk padded to 64, zeroed)
#define P_STR   72
#define O_STR   40
// per-wave scratch layout (elements): qp0 @0 (16x40), qp1 @640 (16x40), P @640 (16x72), o @1152 (16x40)
#define SW_ELEMS 1792

typedef __bf16 bf16x8 __attribute__((ext_vector_type(8)));
typedef float  f32x4  __attribute__((ext_vector_type(4)));
typedef unsigned short u16;
typedef unsigned int   u32;

__device__ __forceinline__ int imin(int a, int b) { return a < b ? a : b; }

__device__ __forceinline__ u16 f2b(float f) {            // fp32 -> bf16 RNE
    u32 u = __builtin_bit_cast(u32, f);
    return (u16)((u + 0x7fffu + ((u >> 16) & 1u)) >> 16);
}
__device__ __forceinline__ float b2f(u16 h) {
    return __builtin_bit_cast(float, ((u32)h) << 16);
}
__device__ __forceinline__ bf16x8 ld_frag(const u16* p) { // 16B frag load (LDS or global)
    uint4 v = *(const uint4*)p;
    return __builtin_bit_cast(bf16x8, v);
}
__device__ __forceinline__ void lds_fence() {
    asm volatile("s_waitcnt lgkmcnt(0)" ::: "memory");
}
#define MFMA(a, b, c) __builtin_amdgcn_mfma_f32_16x16x32_bf16((a), (b), (c), 0, 0, 0)

// ---------------- K0: transpose+convert weights to bf16 in ws ----------------
// ws layout (ushort elems): w_kvT[768][384] @0 ; w_qT[384][192] @294912 ; w_projT[192][384] @368640
__global__ void prep_weights(const float* __restrict__ w_kv, const float* __restrict__ w_q,
                             const float* __restrict__ w_proj, u16* __restrict__ wbuf) {
    int i = blockIdx.x * 512 + threadIdx.x;   // grid covers exactly 442368
    if (i < 294912) {
        int n = i / 384, k = i % 384;
        wbuf[i] = f2b(w_kv[k * 768 + n]);
    } else if (i < 368640) {
        int j = i - 294912;
        int n = j / 192, k = j % 192;
        wbuf[i] = f2b(w_q[k * 384 + n]);
    } else {
        int j = i - 368640;
        int n = j / 384, k = j % 384;
        wbuf[i] = f2b(w_proj[k * 192 + n]);
    }
}

// ---------------- fused per-window kernel ----------------
__global__ __launch_bounds__(512, 2) void wca_fused(
    const float* __restrict__ kv, const float* __restrict__ q,
    const float* __restrict__ b_kv, const float* __restrict__ b_q,
    const float* __restrict__ bias_table, const float* __restrict__ b_proj,
    const u16* __restrict__ wkvT, const u16* __restrict__ wqT, const u16* __restrict__ wprojT,
    float* __restrict__ out) {

    __shared__ u16 qs  [QN * QS_STR];     // 78400 el, q staged bf16
    __shared__ u16 kvs [NKV * KVS_STR];   // 19208 el, kv staged bf16
    __shared__ u16 ks_s[NKV * KS_STR];    // 1960 el, per-head K [kk][d]
    __shared__ u16 vt_s[HD * VT_STR];     // 2304 el, per-head V^T [d][kk], kk-pad zeroed
    __shared__ u16 scratch[8 * SW_ELEMS]; // 14336 el, per-wave bounce buffers
    __shared__ u16 bias_s[169 * 12];      // 2028 el, bias table bf16 (only idx<169 reachable)

    const int tid  = threadIdx.x;
    const int b    = blockIdx.x;
    const int wave = tid >> 6, lane = tid & 63, ln = lane & 15, quad = lane >> 4;

    // ---- stage q (196x192 fp32 -> bf16), kv (49x384), bias table, zero vt ----
    {
        const float4* src = (const float4*)(q + (size_t)b * QN * KQ);
        for (int c = tid; c < QN * KQ / 4; c += 512) {
            int r = c / (KQ / 4), c4 = c % (KQ / 4);
            float4 f = src[c];
            ushort4 u; u.x = f2b(f.x); u.y = f2b(f.y); u.z = f2b(f.z); u.w = f2b(f.w);
            *(ushort4*)&qs[r * QS_STR + c4 * 4] = u;
        }
    }
    {
        const float4* src = (const float4*)(kv + (size_t)b * NKV * DIM);
        for (int c = tid; c < NKV * DIM / 4; c += 512) {
            int r = c / (DIM / 4), c4 = c % (DIM / 4);
            float4 f = src[c];
            ushort4 u; u.x = f2b(f.x); u.y = f2b(f.y); u.z = f2b(f.z); u.w = f2b(f.w);
            *(ushort4*)&kvs[r * KVS_STR + c4 * 4] = u;
        }
    }
    for (int c = tid; c < 169 * 12; c += 512) bias_s[c] = f2b(bias_table[c]);
    for (int c = tid; c < HD * VT_STR; c += 512) vt_s[c] = 0;
    __syncthreads();

    // ---- per-thread constants ----
    const int mkv = wave & 3, pkv = wave >> 2;   // kvp tile assignment (16 tiles / 8 waves)
    const int t0 = wave, t1 = wave + 8;          // attention m-tiles (13 tiles of 16 rows)
    const bool has1 = (t1 < 13);

    int  kterm[4];  bool kval[4];
#pragma unroll
    for (int n = 0; n < 4; n++) {
        int kk = n * 16 + ln;
        int t4 = 4 * kk, ak = t4 / 14, bk = t4 - ak * 14;
        kterm[n] = 84 - 13 * (ak >> 1) - (bk >> 1);
        kval[n]  = (kk < NKV);
    }

    f32x4 pacc[2][12];
#pragma unroll
    for (int mi = 0; mi < 2; mi++)
#pragma unroll
        for (int nt = 0; nt < 12; nt++) pacc[mi][nt] = (f32x4){0.f, 0.f, 0.f, 0.f};

    const u16* kvs_a = &kvs[imin(mkv * 16 + ln, NKV - 1) * KVS_STR + quad * 8];
    const u16* qsa0  = &qs[imin(t0 * 16 + ln, QN - 1) * QS_STR + quad * 8];
    const u16* qsa1  = &qs[imin(t1 * 16 + ln, QN - 1) * QS_STR + quad * 8];
    u16* sw = &scratch[wave * SW_ELEMS];

    for (int h = 0; h < NH; ++h) {
        // ---- kvp: per-head K/V projection (M=49pad64, N=64, K=384) ----
        f32x4 ack = {0.f, 0.f, 0.f, 0.f}, acv = {0.f, 0.f, 0.f, 0.f};
        {
            const int ckrow = h * HD + pkv * 16 + ln;
            const u16* wk0 = &wkvT[(size_t)ckrow * 384 + quad * 8];
            const u16* wk1 = &wkvT[(size_t)(384 + ckrow) * 384 + quad * 8];
#pragma unroll
            for (int k = 0; k < 12; k++) {
                bf16x8 a = ld_frag(kvs_a + k * 32);
                ack = MFMA(a, ld_frag(wk0 + k * 32), ack);
                acv = MFMA(a, ld_frag(wk1 + k * 32), acv);
            }
        }
        {
            const int coll = pkv * 16 + ln;
            float bkb = b_kv[h * HD + coll], bvb = b_kv[384 + h * HD + coll];
#pragma unroll
            for (int r = 0; r < 4; r++) {
                int rg = mkv * 16 + quad * 4 + r;
                if (rg < NKV) {
                    ks_s[rg * KS_STR + coll] = f2b(ack[r] + bkb);
                    vt_s[coll * VT_STR + rg] = f2b(acv[r] + bvb);
                }
            }
        }
        __syncthreads();

        // ---- cache w_projT fragments for this head (K=32 slice) ----
        bf16x8 wp[12];
#pragma unroll
        for (int nt = 0; nt < 12; nt++)
            wp[nt] = ld_frag(&wprojT[(size_t)(nt * 16 + ln) * 384 + h * HD + quad * 8]);

        // ---- qp for both m-tiles (k-outer so w_qT frags load once) ----
        f32x4 qa[2][2];
#pragma unroll
        for (int mi = 0; mi < 2; mi++)
#pragma unroll
            for (int n = 0; n < 2; n++) qa[mi][n] = (f32x4){0.f, 0.f, 0.f, 0.f};
        {
            const u16* wq0 = &wqT[(size_t)(h * HD + ln) * KQ + quad * 8];
            const u16* wq1 = &wqT[(size_t)(h * HD + 16 + ln) * KQ + quad * 8];
#pragma unroll
            for (int k = 0; k < 6; k++) {
                bf16x8 b0 = ld_frag(wq0 + k * 32);
                bf16x8 b1 = ld_frag(wq1 + k * 32);
                bf16x8 a0 = ld_frag(qsa0 + k * 32);
                qa[0][0] = MFMA(a0, b0, qa[0][0]);
                qa[0][1] = MFMA(a0, b1, qa[0][1]);
                if (has1) {
                    bf16x8 a1 = ld_frag(qsa1 + k * 32);
                    qa[1][0] = MFMA(a1, b0, qa[1][0]);
                    qa[1][1] = MFMA(a1, b1, qa[1][1]);
                }
            }
        }
        {
            float bq0 = b_q[h * HD + ln], bq1 = b_q[h * HD + 16 + ln];
#pragma unroll
            for (int mi = 0; mi < 2; mi++) {
                if (mi && !has1) break;
#pragma unroll
                for (int r = 0; r < 4; r++) {
                    sw[mi * 640 + (quad * 4 + r) * O_STR + ln]      = f2b((qa[mi][0][r] + bq0) * SCALE);
                    sw[mi * 640 + (quad * 4 + r) * O_STR + 16 + ln] = f2b((qa[mi][1][r] + bq1) * SCALE);
                }
            }
        }
        lds_fence();

        // ---- attention per m-tile; process mi=1 first (P region overlaps qp1 slot) ----
#pragma unroll
        for (int mi2 = 0; mi2 < 2; mi2++) {
            int mi = 1 - mi2;
            if (mi == 1 && !has1) continue;
            int t = mi ? t1 : t0;

            bf16x8 aq = ld_frag(&sw[mi * 640 + ln * O_STR + quad * 8]);
            f32x4 s[4];
#pragma unroll
            for (int n = 0; n < 4; n++) {
                bf16x8 bk = ld_frag(&ks_s[imin(n * 16 + ln, NKV - 1) * KS_STR + quad * 8]);
                f32x4 z = {0.f, 0.f, 0.f, 0.f};
                s[n] = MFMA(aq, bk, z);
            }
            float rsum[4];
#pragma unroll
            for (int r = 0; r < 4; r++) {
                int qrow = t * 16 + quad * 4 + r;
                int qb = imin(qrow, QN - 1);
                int aqd = qb / 14, bqd = qb - aqd * 14;
                int qterm = 13 * (aqd >> 1) + (bqd >> 1);
                float sv[4];
#pragma unroll
                for (int n = 0; n < 4; n++) {
                    if (kval[n]) sv[n] = s[n][r] + b2f(bias_s[(qterm + kterm[n]) * 12 + h]);
                    else         sv[n] = -1e30f;
                }
                float mx = fmaxf(fmaxf(sv[0], sv[1]), fmaxf(sv[2], sv[3]));
                mx = fmaxf(mx, __shfl_xor(mx, 1));
                mx = fmaxf(mx, __shfl_xor(mx, 2));
                mx = fmaxf(mx, __shfl_xor(mx, 4));
                mx = fmaxf(mx, __shfl_xor(mx, 8));
                float e[4], sum = 0.f;
#pragma unroll
                for (int n = 0; n < 4; n++) { e[n] = __expf(sv[n] - mx); sum += e[n]; }
                sum += __shfl_xor(sum, 1);
                sum += __shfl_xor(sum, 2);
                sum += __shfl_xor(sum, 4);
                sum += __shfl_xor(sum, 8);
                rsum[r] = sum;
#pragma unroll
                for (int n = 0; n < 4; n++)
                    sw[640 + (quad * 4 + r) * P_STR + n * 16 + ln] = f2b(e[n]);
            }
            lds_fence();

            // PV: o = P @ V^T   (M=16, N=32, K=64)
            bf16x8 ap0 = ld_frag(&sw[640 + ln * P_STR + quad * 8]);
            bf16x8 ap1 = ld_frag(&sw[640 + ln * P_STR + 32 + quad * 8]);
            bf16x8 bv00 = ld_frag(&vt_s[ln * VT_STR + quad * 8]);
            bf16x8 bv01 = ld_frag(&vt_s[ln * VT_STR + 32 + quad * 8]);
            bf16x8 bv10 = ld_frag(&vt_s[(16 + ln) * VT_STR + quad * 8]);
            bf16x8 bv11 = ld_frag(&vt_s[(16 + ln) * VT_STR + 32 + quad * 8]);
            f32x4 o0 = {0.f, 0.f, 0.f, 0.f}, o1 = {0.f, 0.f, 0.f, 0.f};
            o0 = MFMA(ap0, bv00, o0); o0 = MFMA(ap1, bv01, o0);
            o1 = MFMA(ap0, bv10, o1); o1 = MFMA(ap1, bv11, o1);
            lds_fence();  // P reads complete before o overwrites its tail
#pragma unroll
            for (int r = 0; r < 4; r++) {
                float rinv = 1.0f / rsum[r];
                sw[1152 + (quad * 4 + r) * O_STR + ln]      = f2b(o0[r] * rinv);
                sw[1152 + (quad * 4 + r) * O_STR + 16 + ln] = f2b(o1[r] * rinv);
            }
            lds_fence();

            // proj: accumulate o_h @ w_projT (K=32 head slice) into persistent acc
            bf16x8 ao = ld_frag(&sw[1152 + ln * O_STR + quad * 8]);
#pragma unroll
            for (int nt = 0; nt < 12; nt++) pacc[mi][nt] = MFMA(ao, wp[nt], pacc[mi][nt]);
        }
        __syncthreads();  // everyone done with ks_s/vt_s before next head's kvp overwrites
    }

    // ---- epilogue: out = pacc + b_proj ----
#pragma unroll
    for (int mi = 0; mi < 2; mi++) {
        if (mi && !has1) break;
        int t = mi ? t1 : t0;
#pragma unroll
        for (int r = 0; r < 4; r++) {
            int qrow = t * 16 + quad * 4 + r;
            if (qrow < QN) {
                float* orow = out + ((size_t)b * QN + qrow) * KQ;
#pragma unroll
                for (int nt = 0; nt < 12; nt++)
                    orow[nt * 16 + ln] = pacc[mi][nt][r] + b_proj[nt * 16 + ln];
            }
        }
    }
}

extern "C" void kernel_launch(void* const* d_in, const int* in_sizes, int n_in,
                              void* d_out, int out_size, void* d_ws, size_t ws_size,
                              hipStream_t stream) {
    (void)in_sizes; (void)n_in; (void)out_size; (void)ws_size;
    const float* kv         = (const float*)d_in[0];
    const float* q          = (const float*)d_in[1];
    const float* w_kv       = (const float*)d_in[2];
    const float* b_kv       = (const float*)d_in[3];
    const float* w_q        = (const float*)d_in[4];
    const float* b_q        = (const float*)d_in[5];
    const float* bias_table = (const float*)d_in[6];
    const float* w_proj     = (const float*)d_in[7];
    const float* b_proj     = (const float*)d_in[8];
    float* out = (float*)d_out;
    u16* wbuf = (u16*)d_ws;   // 442368 ushorts = 884736 B

    prep_weights<<<864, 512, 0, stream>>>(w_kv, w_q, w_proj, wbuf);
    wca_fused<<<BWIN, 512, 0, stream>>>(kv, q, b_kv, b_q, bias_table, b_proj,
                                        wbuf, wbuf + 294912, wbuf + 368640, out);
}